// Round 1
// baseline (349.968 us; speedup 1.0000x reference)
//
#include <hip/hip_runtime.h>
#include <hip/hip_bf16.h>

// EdgeBlock fused MLP:
//   out = relu(concat(edge, node[recv], node[send], g) @ W1 + b1) @ W2 + b2
// E=640000, N=10000, D=128, H=256, O=128.
//
// Strategy:
//  - bf16 MFMA (16x16x32), fp32 accumulate. Threshold is bf16-tier (8.375e-2).
//  - Fold g@W1[384:512]+b1 into a precomputed 256-wide bias (K: 512->384).
//  - Prep kernels: node_attr -> bf16 table (L2-resident), W1/W2 -> bf16 in
//    MFMA-B fragment-packed order, bias vector.
//  - Main kernel: 64 edges/block, 4 waves. Edge seg staged f32->bf16 in
//    XOR-swizzled LDS; node segs gathered straight from bf16 table into
//    A-fragments; h transposed through swizzled LDS into GEMM2.

typedef __attribute__((ext_vector_type(8))) short bf16x8;
typedef __attribute__((ext_vector_type(4))) float f32x4;

static __device__ __forceinline__ unsigned short f2bf(float f) {
    unsigned u = __builtin_bit_cast(unsigned, f);
    u += 0x7FFFu + ((u >> 16) & 1u);   // round-to-nearest-even
    return (unsigned short)(u >> 16);
}

// ---------------- prep kernels ----------------

// node_attr [10000][128] f32 -> bf16, 8 elems/thread
__global__ void prep_node_kernel(const float* __restrict__ node,
                                 ushort* __restrict__ nb) {
    int i = blockIdx.x * 256 + threadIdx.x;   // 0..159999
    if (i >= 160000) return;
    const float4* s = (const float4*)(node + (size_t)i * 8);
    float4 a = s[0], b = s[1];
    ushort tmp[8] = { f2bf(a.x), f2bf(a.y), f2bf(a.z), f2bf(a.w),
                      f2bf(b.x), f2bf(b.y), f2bf(b.z), f2bf(b.w) };
    *(bf16x8*)&nb[(size_t)i * 8] = *(bf16x8*)tmp;
}

// W1 [512][256] f32 (rows 0..383 used) -> fragment-packed bf16:
// block = gnt*12 + ks (gnt: n-tile of 16, ks: k-step of 32); within block,
// lane l holds 8 elems: n = gnt*16 + (l&15), k = ks*32 + (l>>4)*8 + j.
__global__ void prep_w1_kernel(const float* __restrict__ W1,
                               ushort* __restrict__ w1f) {
    int id = blockIdx.x * 256 + threadIdx.x;  // 0..12287
    if (id >= 16 * 12 * 64) return;
    int l = id & 63, blk = id >> 6;
    int ks = blk % 12, gnt = blk / 12;
    int n  = gnt * 16 + (l & 15);
    int k0 = ks * 32 + (l >> 4) * 8;
    ushort tmp[8];
    #pragma unroll
    for (int j = 0; j < 8; ++j) tmp[j] = f2bf(W1[(k0 + j) * 256 + n]);
    *(bf16x8*)&w1f[(size_t)id * 8] = *(bf16x8*)tmp;
}

// W2 [256][128] f32 -> fragment-packed bf16 (8 n-tiles, 8 k-steps)
__global__ void prep_w2_kernel(const float* __restrict__ W2,
                               ushort* __restrict__ w2f) {
    int id = blockIdx.x * 256 + threadIdx.x;  // 0..4095
    if (id >= 8 * 8 * 64) return;
    int l = id & 63, blk = id >> 6;
    int ks = blk % 8, gnt = blk / 8;
    int n  = gnt * 16 + (l & 15);
    int k0 = ks * 32 + (l >> 4) * 8;
    ushort tmp[8];
    #pragma unroll
    for (int j = 0; j < 8; ++j) tmp[j] = f2bf(W2[(k0 + j) * 128 + n]);
    *(bf16x8*)&w2f[(size_t)id * 8] = *(bf16x8*)tmp;
}

// hbias[n] = b1[n] + sum_k g[k] * W1[384+k][n]   (fp32, exact global fold)
__global__ void prep_hbias_kernel(const float* __restrict__ W1,
                                  const float* __restrict__ b1,
                                  const float* __restrict__ g,
                                  float* __restrict__ hbias) {
    int n = threadIdx.x;  // 256 threads, 1 block
    float acc = b1[n];
    for (int k = 0; k < 128; ++k) acc += g[k] * W1[(384 + k) * 256 + n];
    hbias[n] = acc;
}

// ---------------- main fused kernel ----------------

__global__ __launch_bounds__(256, 2) void edge_mlp_kernel(
    const float* __restrict__ edge_attr,   // [E][128] f32
    const int* __restrict__ senders,
    const int* __restrict__ receivers,
    const ushort* __restrict__ node_bf,    // [N][128] bf16
    const ushort* __restrict__ w1f,        // frag-packed
    const ushort* __restrict__ w2f,        // frag-packed
    const float* __restrict__ hbias,       // [256]
    const float* __restrict__ b2,          // [128]
    float* __restrict__ out)               // [E][128] f32
{
    __shared__ ushort Xe[64 * 128];   // 16 KiB, swizzled
    __shared__ ushort Hs[64 * 256];   // 32 KiB, swizzled

    const int t   = threadIdx.x;
    const int l   = t & 63;
    const int wid = t >> 6;
    const int base = blockIdx.x * 64;

    const int lr = l & 15;           // MFMA row/col within 16
    const int lk = (l >> 4) * 8;     // MFMA k sub-offset within 32

    // ---- stage edge segment: f32 -> bf16 into swizzled LDS ----
    #pragma unroll
    for (int p = 0; p < 4; ++p) {
        int chunk = p * 256 + t;           // 0..1023 (64 rows x 16 chunks)
        int r  = chunk >> 4;
        int c0 = (chunk & 15) * 8;
        const float4* src = (const float4*)(edge_attr + (size_t)(base + r) * 128 + c0);
        float4 a = src[0];
        float4 b = src[1];
        ushort tmp[8] = { f2bf(a.x), f2bf(a.y), f2bf(a.z), f2bf(a.w),
                          f2bf(b.x), f2bf(b.y), f2bf(b.z), f2bf(b.w) };
        *(bf16x8*)&Xe[r * 128 + (c0 ^ ((r & 7) << 3))] = *(bf16x8*)tmp;
    }

    // per-lane gather row offsets for the 4 m-tiles
    int nrow[4], srow[4];
    #pragma unroll
    for (int mt = 0; mt < 4; ++mt) {
        int e = base + mt * 16 + lr;
        nrow[mt] = receivers[e] * 128;
        srow[mt] = senders[e]   * 128;
    }

    __syncthreads();

    // ---- GEMM1: h[64][256] = X[64][384] @ W1, fp32 acc ----
    f32x4 acc[4][4];
    #pragma unroll
    for (int mt = 0; mt < 4; ++mt)
        #pragma unroll
        for (int nt = 0; nt < 4; ++nt)
            acc[mt][nt] = (f32x4){0.f, 0.f, 0.f, 0.f};

    #pragma unroll
    for (int ks = 0; ks < 12; ++ks) {
        bf16x8 B[4];
        #pragma unroll
        for (int nt = 0; nt < 4; ++nt) {
            int gnt = wid * 4 + nt;
            B[nt] = *(const bf16x8*)&w1f[(size_t)((gnt * 12 + ks) * 64 + l) * 8];
        }
        bf16x8 A[4];
        const int seg = ks >> 2;
        const int kk  = (ks & 3) * 32 + lk;
        if (seg == 0) {
            #pragma unroll
            for (int mt = 0; mt < 4; ++mt) {
                int row = mt * 16 + lr;
                A[mt] = *(const bf16x8*)&Xe[row * 128 + (kk ^ ((row & 7) << 3))];
            }
        } else if (seg == 1) {
            #pragma unroll
            for (int mt = 0; mt < 4; ++mt)
                A[mt] = *(const bf16x8*)&node_bf[nrow[mt] + kk];
        } else {
            #pragma unroll
            for (int mt = 0; mt < 4; ++mt)
                A[mt] = *(const bf16x8*)&node_bf[srow[mt] + kk];
        }
        #pragma unroll
        for (int mt = 0; mt < 4; ++mt)
            #pragma unroll
            for (int nt = 0; nt < 4; ++nt)
                acc[mt][nt] = __builtin_amdgcn_mfma_f32_16x16x32_bf16(
                    A[mt], B[nt], acc[mt][nt], 0, 0, 0);
    }

    // epilogue 1: +bias, relu, bf16, swizzled transpose through LDS
    float hb[4];
    #pragma unroll
    for (int nt = 0; nt < 4; ++nt)
        hb[nt] = hbias[wid * 64 + nt * 16 + lr];

    #pragma unroll
    for (int mt = 0; mt < 4; ++mt)
        #pragma unroll
        for (int nt = 0; nt < 4; ++nt)
            #pragma unroll
            for (int j = 0; j < 4; ++j) {
                float v = acc[mt][nt][j] + hb[nt];
                v = fmaxf(v, 0.0f);
                int row = mt * 16 + (l >> 4) * 4 + j;
                int col = wid * 64 + nt * 16 + lr;
                Hs[row * 256 + (col ^ ((row & 7) << 3))] = f2bf(v);
            }

    __syncthreads();

    // ---- GEMM2: out[64][128] = h[64][256] @ W2 ----
    f32x4 acc2[4][2];
    #pragma unroll
    for (int mt = 0; mt < 4; ++mt)
        #pragma unroll
        for (int nt = 0; nt < 2; ++nt)
            acc2[mt][nt] = (f32x4){0.f, 0.f, 0.f, 0.f};

    #pragma unroll
    for (int ks = 0; ks < 8; ++ks) {
        bf16x8 B2[2];
        #pragma unroll
        for (int nt = 0; nt < 2; ++nt) {
            int gnt = wid * 2 + nt;
            B2[nt] = *(const bf16x8*)&w2f[(size_t)((gnt * 8 + ks) * 64 + l) * 8];
        }
        bf16x8 A2[4];
        const int kk = ks * 32 + lk;
        #pragma unroll
        for (int mt = 0; mt < 4; ++mt) {
            int row = mt * 16 + lr;
            A2[mt] = *(const bf16x8*)&Hs[row * 256 + (kk ^ ((row & 7) << 3))];
        }
        #pragma unroll
        for (int mt = 0; mt < 4; ++mt)
            #pragma unroll
            for (int nt = 0; nt < 2; ++nt)
                acc2[mt][nt] = __builtin_amdgcn_mfma_f32_16x16x32_bf16(
                    A2[mt], B2[nt], acc2[mt][nt], 0, 0, 0);
    }

    // epilogue 2: +b2, store f32
    float b2v[2];
    #pragma unroll
    for (int nt = 0; nt < 2; ++nt)
        b2v[nt] = b2[wid * 32 + nt * 16 + lr];

    #pragma unroll
    for (int mt = 0; mt < 4; ++mt)
        #pragma unroll
        for (int nt = 0; nt < 2; ++nt)
            #pragma unroll
            for (int j = 0; j < 4; ++j) {
                int row = base + mt * 16 + (l >> 4) * 4 + j;
                int col = wid * 32 + nt * 16 + lr;
                out[(size_t)row * 128 + col] = acc2[mt][nt][j] + b2v[nt];
            }
}

// ---------------- launcher ----------------

extern "C" void kernel_launch(void* const* d_in, const int* in_sizes, int n_in,
                              void* d_out, int out_size, void* d_ws, size_t ws_size,
                              hipStream_t stream) {
    (void)in_sizes; (void)n_in; (void)out_size; (void)ws_size;

    const float* edge_attr   = (const float*)d_in[0];  // [640000][128]
    const float* node_attr   = (const float*)d_in[1];  // [10000][128]
    const float* global_attr = (const float*)d_in[2];  // [128]
    const int*   senders     = (const int*)d_in[3];
    const int*   receivers   = (const int*)d_in[4];
    const float* W1          = (const float*)d_in[5];  // [512][256]
    const float* b1          = (const float*)d_in[6];  // [256]
    const float* W2          = (const float*)d_in[7];  // [256][128]
    const float* b2          = (const float*)d_in[8];  // [128]
    float* out = (float*)d_out;

    // workspace layout (all 16B aligned)
    ushort* node_bf = (ushort*)d_ws;                           // 2,560,000 B
    ushort* w1f     = (ushort*)((char*)d_ws + 2560000);        //   196,608 B
    ushort* w2f     = (ushort*)((char*)d_ws + 2756608);        //    65,536 B
    float*  hbias   = (float*)((char*)d_ws + 2822144);         //     1,024 B

    hipLaunchKernelGGL(prep_node_kernel,  dim3(625), dim3(256), 0, stream, node_attr, node_bf);
    hipLaunchKernelGGL(prep_w1_kernel,    dim3(48),  dim3(256), 0, stream, W1, w1f);
    hipLaunchKernelGGL(prep_w2_kernel,    dim3(16),  dim3(256), 0, stream, W2, w2f);
    hipLaunchKernelGGL(prep_hbias_kernel, dim3(1),   dim3(256), 0, stream, W1, b1, global_attr, hbias);

    hipLaunchKernelGGL(edge_mlp_kernel, dim3(10000), dim3(256), 0, stream,
                       edge_attr, senders, receivers, node_bf, w1f, w2f, hbias, b2, out);
}